// Round 4
// baseline (160.946 us; speedup 1.0000x reference)
//
#include <hip/hip_runtime.h>
#include <hip/hip_bf16.h>

typedef __bf16 bf16x8 __attribute__((ext_vector_type(8)));
typedef float f32x4 __attribute__((ext_vector_type(4)));

typedef __attribute__((address_space(1))) void gv_t;
typedef __attribute__((address_space(3))) void lv_t;

__device__ __forceinline__ unsigned short f2bf(float f) {
    unsigned int u = __float_as_uint(f);
    unsigned int r = (u + 0x7fffu + ((u >> 16) & 1u)) >> 16;
    return (unsigned short)r;
}

__device__ __forceinline__ unsigned int cvt_pk_bf16(float a, float b) {
    unsigned int r;
    asm("v_cvt_pk_bf16_f32 %0, %1, %2" : "=v"(r) : "v"(a), "v"(b));
    return r;
}

// ---------------------------------------------------------------- convert x
__global__ void convert_f32_bf16(const float* __restrict__ in,
                                 unsigned short* __restrict__ out, int n4) {
    int i = blockIdx.x * blockDim.x + threadIdx.x;
    if (i >= n4) return;
    float4 v = reinterpret_cast<const float4*>(in)[i];
    ushort4 o;
    o.x = f2bf(v.x); o.y = f2bf(v.y); o.z = f2bf(v.z); o.w = f2bf(v.w);
    reinterpret_cast<ushort4*>(out)[i] = o;
}

// ------------------------------------------------- transpose + convert W
__global__ void transpose_convert(const float* __restrict__ in,
                                  unsigned short* __restrict__ out,
                                  int K, int N) {
    __shared__ float t[32][33];
    int n0 = blockIdx.x * 32, k0 = blockIdx.y * 32;
    t[threadIdx.y][threadIdx.x] = in[(size_t)(k0 + threadIdx.y) * N + (n0 + threadIdx.x)];
    __syncthreads();
    out[(size_t)(n0 + threadIdx.y) * K + (k0 + threadIdx.x)] = f2bf(t[threadIdx.x][threadIdx.y]);
}

// ---------------------------------------------------------------- GEMM
// C[M,N] = A[M,K] bf16 @ Bt[N,K]^T bf16 [+ bias] [cols<1024 scaled 0.125]
template <bool BIAS, bool OUT_BF16, bool QSCALE>
__global__ __launch_bounds__(256) void gemm_bt(const unsigned short* __restrict__ A,
                                               const unsigned short* __restrict__ Bt,
                                               const float* __restrict__ bias,
                                               void* __restrict__ Cv,
                                               int M, int N, int K) {
    __shared__ alignas(16) unsigned short As[128 * 32];
    __shared__ alignas(16) unsigned short Bs[128 * 32];

    const int t = threadIdx.x;
    const int lane = t & 63;
    const int wid = t >> 6;
    const int wr = wid >> 1, wc = wid & 1;
    const int m0 = blockIdx.y * 128, n0 = blockIdx.x * 128;

    f32x4 acc[4][4] = {};

    for (int k0 = 0; k0 < K; k0 += 32) {
#pragma unroll
        for (int i = 0; i < 2; ++i) {
            int c = i * 256 + t;
            int row = c >> 2;
            int col = (c & 3) * 8;
            const unsigned short* ga = A + (size_t)(m0 + row) * K + k0 + col;
            const unsigned short* gb = Bt + (size_t)(n0 + row) * K + k0 + col;
            __builtin_amdgcn_global_load_lds((gv_t*)ga, (lv_t*)(As + c * 8), 16, 0, 0);
            __builtin_amdgcn_global_load_lds((gv_t*)gb, (lv_t*)(Bs + c * 8), 16, 0, 0);
        }
        __syncthreads();

        bf16x8 af[4], bfr[4];
#pragma unroll
        for (int i = 0; i < 4; ++i)
            af[i] = *reinterpret_cast<const bf16x8*>(As + (wr * 64 + i * 16 + (lane & 15)) * 32 + (lane >> 4) * 8);
#pragma unroll
        for (int j = 0; j < 4; ++j)
            bfr[j] = *reinterpret_cast<const bf16x8*>(Bs + (wc * 64 + j * 16 + (lane & 15)) * 32 + (lane >> 4) * 8);
#pragma unroll
        for (int i = 0; i < 4; ++i)
#pragma unroll
            for (int j = 0; j < 4; ++j)
                acc[i][j] = __builtin_amdgcn_mfma_f32_16x16x32_bf16(af[i], bfr[j], acc[i][j], 0, 0, 0);
        __syncthreads();
    }

#pragma unroll
    for (int i = 0; i < 4; ++i) {
        int row = m0 + wr * 64 + i * 16 + (lane >> 4) * 4;
#pragma unroll
        for (int j = 0; j < 4; ++j) {
            int col = n0 + wc * 64 + j * 16 + (lane & 15);
            float bv = 0.0f;
            if (BIAS) bv = bias[col];
#pragma unroll
            for (int r = 0; r < 4; ++r) {
                float v = acc[i][j][r] + bv;
                if constexpr (QSCALE) { if (col < 1024) v *= 0.125f; }
                if constexpr (OUT_BF16)
                    ((unsigned short*)Cv)[(size_t)(row + r) * N + col] = f2bf(v);
                else
                    ((float*)Cv)[(size_t)(row + r) * N + col] = v;
            }
        }
    }
}

// ---------------------------------------------------------- flash attention
// Swapped-operand flash attn, double-buffered K/V, async stage split,
// defer-max. One block per (b,h,q-tile); qt = 31 - blockIdx.x (LPT: longest
// first). 4 waves; wave owns 16 q-rows; lane owns q = w*16 + (lane&15).
__global__ __launch_bounds__(256) void attn_fwd(const unsigned short* __restrict__ qkv,
                                                unsigned short* __restrict__ ctx,
                                                int S) {
    const int TD = 3072, D = 1024;
    __shared__ alignas(16) unsigned short Ks[2][64 * 64];   // [kv][hd], swizzled
    __shared__ alignas(16) unsigned short Vt[2][64 * 64];   // [hd][kv], swizzled
    __shared__ alignas(16) unsigned short Ps[4][16 * 64];   // per-wave [q][kv], swizzled

    const int t = threadIdx.x, lane = t & 63, w = t >> 6;
    const int l15 = lane & 15, l4 = lane >> 4;
    const int qt = 31 - (int)blockIdx.x;     // LPT: long blocks dispatch first
    const int bh = blockIdx.y;
    const int b = bh >> 4, h = bh & 15;

    const size_t base = ((size_t)b * S) * TD + (size_t)h * 64;
    const unsigned short* qp = qkv + base;
    const unsigned short* kp = qkv + base + D;
    const unsigned short* vp = qkv + base + 2 * D;

    // Q fragments straight from global (B-operand layout: n=q=lane&15)
    bf16x8 aq[2];
    {
        const unsigned short* g = qp + (size_t)(qt * 64 + w * 16 + l15) * TD + l4 * 8;
        aq[0] = *reinterpret_cast<const bf16x8*>(g);
        aq[1] = *reinterpret_cast<const bf16x8*>(g + 32);
    }

    f32x4 oc[4] = {};                        // O^T frags: row=hd, col=q
    float mR = -1e30f, lR = 0.f;

    const float L2E = 1.44269504f;

    // ---- staging helpers
    auto stageK = [&](int j0, int buf) {
#pragma unroll
        for (int rnd = 0; rnd < 2; ++rnd) {
            int c = rnd * 256 + t;
            int row = c >> 3, hh = c & 7;
            const unsigned short* src = kp + (size_t)(j0 * 64 + row) * TD + ((hh ^ (row & 7)) * 8);
            __builtin_amdgcn_global_load_lds((gv_t*)src, (lv_t*)(Ks[buf] + c * 8), 16, 0, 0);
        }
    };
    const int v_hd = (t & 31) * 2, v_kvb = (t >> 5) * 8;
    unsigned int vv[8];
    auto loadV = [&](int j0) {
        const unsigned short* vsrc = vp + (size_t)(j0 * 64 + v_kvb) * TD + v_hd;
#pragma unroll
        for (int e = 0; e < 8; ++e)
            vv[e] = *reinterpret_cast<const unsigned int*>(vsrc + (size_t)e * TD);
    };
    auto writeV = [&](int buf) {
        unsigned int r0[4], r1[4];
#pragma unroll
        for (int i = 0; i < 4; ++i) {
            r0[i] = __builtin_amdgcn_perm(vv[2 * i + 1], vv[2 * i], 0x05040100u);
            r1[i] = __builtin_amdgcn_perm(vv[2 * i + 1], vv[2 * i], 0x07060302u);
        }
        int g0 = (v_kvb >> 3) ^ (v_hd & 7);
        int g1 = (v_kvb >> 3) ^ ((v_hd + 1) & 7);
        *reinterpret_cast<uint4*>(Vt[buf] + v_hd * 64 + g0 * 8) = make_uint4(r0[0], r0[1], r0[2], r0[3]);
        *reinterpret_cast<uint4*>(Vt[buf] + (v_hd + 1) * 64 + g1 * 8) = make_uint4(r1[0], r1[1], r1[2], r1[3]);
    };

    auto compute = [&](bool diag, int buf) {
        // ---- S^T = mfma(K, Q): lane holds kv = jn*16 + l4*4 + r for q = w*16+l15
        f32x4 sc[4];
        __builtin_amdgcn_s_setprio(1);
#pragma unroll
        for (int jn = 0; jn < 4; ++jn) {
            f32x4 s = {};
#pragma unroll
            for (int kk = 0; kk < 2; ++kk) {
                int row = jn * 16 + l15;
                int g = (kk * 4 + l4) ^ (l15 & 7);
                bf16x8 ak = *reinterpret_cast<const bf16x8*>(Ks[buf] + row * 64 + g * 8);
                s = __builtin_amdgcn_mfma_f32_16x16x32_bf16(ak, aq[kk], s, 0, 0, 0);
            }
            sc[jn] = s;
        }
        __builtin_amdgcn_s_setprio(0);
        if (diag) {
            int ql = w * 16 + l15;
#pragma unroll
            for (int jn = 0; jn < 4; ++jn)
#pragma unroll
                for (int r = 0; r < 4; ++r)
                    if (jn * 16 + l4 * 4 + r > ql) sc[jn][r] = -1e30f;
        }
        // ---- online softmax (lane-local row), defer-max (THR=8)
        float pm = -1e30f;
#pragma unroll
        for (int jn = 0; jn < 4; ++jn)
            pm = fmaxf(fmaxf(pm, fmaxf(sc[jn][0], sc[jn][1])),
                       fmaxf(sc[jn][2], sc[jn][3]));
        pm = fmaxf(pm, __shfl_xor(pm, 16));
        pm = fmaxf(pm, __shfl_xor(pm, 32));
        if (__any(pm > mR + 8.0f)) {         // rescale only when max grew
            float mnew = fmaxf(mR, pm);
            float alpha = exp2f((mR - mnew) * L2E);
            mR = mnew;
            lR *= alpha;
#pragma unroll
            for (int jc = 0; jc < 4; ++jc) oc[jc] *= alpha;
        }
        float mn2 = mR * L2E;
        float ps = 0.f;
#pragma unroll
        for (int jn = 0; jn < 4; ++jn) {
            float p0 = exp2f(sc[jn][0] * L2E - mn2);
            float p1 = exp2f(sc[jn][1] * L2E - mn2);
            float p2 = exp2f(sc[jn][2] * L2E - mn2);
            float p3 = exp2f(sc[jn][3] * L2E - mn2);
            sc[jn][0] = p0; sc[jn][1] = p1; sc[jn][2] = p2; sc[jn][3] = p3;
            ps += (p0 + p1) + (p2 + p3);
        }
        ps += __shfl_xor(ps, 16);
        ps += __shfl_xor(ps, 32);
        lR += ps;
        // ---- P^T -> Ps[w] via cvt_pk + b64 writes (granule-swizzled by q)
        const int q = l15;
#pragma unroll
        for (int jn = 0; jn < 4; ++jn) {
            unsigned int lo = cvt_pk_bf16(sc[jn][0], sc[jn][1]);
            unsigned int hi = cvt_pk_bf16(sc[jn][2], sc[jn][3]);
            int kv0 = jn * 16 + l4 * 4;
            int g = (kv0 >> 3) ^ (q & 7);
            *reinterpret_cast<uint2*>(Ps[w] + q * 64 + g * 8 + (kv0 & 7)) = make_uint2(lo, hi);
        }
        // ---- O^T += mfma(V^T, P)
        __builtin_amdgcn_s_setprio(1);
#pragma unroll
        for (int kk = 0; kk < 2; ++kk) {
            int gq = (kk * 4 + l4) ^ (q & 7);
            bf16x8 bp = *reinterpret_cast<const bf16x8*>(Ps[w] + q * 64 + gq * 8);
#pragma unroll
            for (int jc = 0; jc < 4; ++jc) {
                int hdrow = jc * 16 + l15;
                int gv = (kk * 4 + l4) ^ (l15 & 7);
                bf16x8 av = *reinterpret_cast<const bf16x8*>(Vt[buf] + hdrow * 64 + gv * 8);
                oc[jc] = __builtin_amdgcn_mfma_f32_16x16x32_bf16(av, bp, oc[jc], 0, 0, 0);
            }
        }
        __builtin_amdgcn_s_setprio(0);
    };

    // ---- prologue: stage tile 0 into buf 0
    stageK(0, 0);
    loadV(0);
    writeV(0);
    __syncthreads();

    for (int j0 = 0; j0 <= qt; ++j0) {
        const int cur = j0 & 1, nxt = cur ^ 1;
        const bool have_next = (j0 < qt);
        if (have_next) {          // issue next tile's loads before compute
            stageK(j0 + 1, nxt);
            loadV(j0 + 1);
        }
        compute(j0 == qt, cur);
        if (have_next) writeV(nxt);   // waits vmcnt for vv, then ds_write
        __syncthreads();
    }

    // ---- epilogue: ctx[q][hd] = O^T / l  (cvt_pk + b64 stores)
    {
        float inv = 1.0f / lR;
        size_t qg = (size_t)qt * 64 + w * 16 + l15;
        unsigned short* crow = ctx + ((size_t)b * S + qg) * D + h * 64;
#pragma unroll
        for (int jc = 0; jc < 4; ++jc) {
            unsigned int pk0 = cvt_pk_bf16(oc[jc][0] * inv, oc[jc][1] * inv);
            unsigned int pk1 = cvt_pk_bf16(oc[jc][2] * inv, oc[jc][3] * inv);
            *reinterpret_cast<uint2*>(crow + jc * 16 + l4 * 4) = make_uint2(pk0, pk1);
        }
    }
}

// ---------------------------------------------------------------- launch
extern "C" void kernel_launch(void* const* d_in, const int* in_sizes, int n_in,
                              void* d_out, int out_size, void* d_ws, size_t ws_size,
                              hipStream_t stream) {
    const float* x = (const float*)d_in[0];
    const float* Wqkv = (const float*)d_in[1];
    const float* bqkv = (const float*)d_in[2];
    const float* Wout = (const float*)d_in[3];
    float* out = (float*)d_out;

    const int B = 2, S = 2048, D = 1024, TD = 3072;
    const int M = B * S;  // 4096

    char* ws = (char*)d_ws;
    unsigned short* x_bf  = (unsigned short*)(ws);               // 8 MiB
    unsigned short* wqkvT = (unsigned short*)(ws + 8388608);     // 6 MiB  [3072][1024]
    unsigned short* woutT = (unsigned short*)(ws + 14680064);    // 2 MiB  [1024][1024]
    unsigned short* qkv   = (unsigned short*)(ws + 16777216);    // 24 MiB [4096][3072]
    unsigned short* ctx   = (unsigned short*)(ws + 41943040);    // 8 MiB  [4096][1024]

    convert_f32_bf16<<<dim3((M * D / 4 + 255) / 256), dim3(256), 0, stream>>>(x, x_bf, M * D / 4);
    transpose_convert<<<dim3(TD / 32, D / 32), dim3(32, 32), 0, stream>>>(Wqkv, wqkvT, D, TD);
    transpose_convert<<<dim3(D / 32, D / 32), dim3(32, 32), 0, stream>>>(Wout, woutT, D, D);

    gemm_bt<true, true, true><<<dim3(TD / 128, M / 128), dim3(256), 0, stream>>>(
        x_bf, wqkvT, bqkv, (void*)qkv, M, TD, D);

    attn_fwd<<<dim3(32, 32), dim3(256), 0, stream>>>(qkv, ctx, S);

    gemm_bt<false, false, false><<<dim3(D / 128, M / 128), dim3(256), 0, stream>>>(
        ctx, woutT, nullptr, (void*)out, M, D, D);
}

// Round 5
// 157.088 us; speedup vs baseline: 1.0246x; 1.0246x over previous
//
#include <hip/hip_runtime.h>
#include <hip/hip_bf16.h>

typedef __bf16 bf16x8 __attribute__((ext_vector_type(8)));
typedef float f32x4 __attribute__((ext_vector_type(4)));
typedef unsigned short ushortx8 __attribute__((ext_vector_type(8)));

typedef __attribute__((address_space(1))) void gv_t;
typedef __attribute__((address_space(3))) void lv_t;

__device__ __forceinline__ unsigned short f2bf(float f) {
    unsigned int u = __float_as_uint(f);
    unsigned int r = (u + 0x7fffu + ((u >> 16) & 1u)) >> 16;
    return (unsigned short)r;
}

__device__ __forceinline__ unsigned int cvt_pk_bf16(float a, float b) {
    unsigned int r;
    asm("v_cvt_pk_bf16_f32 %0, %1, %2" : "=v"(r) : "v"(a), "v"(b));
    return r;
}

__device__ __forceinline__ float bf2f(unsigned short u) {
    return __uint_as_float(((unsigned int)u) << 16);
}

// ---------------------------------------------------------------- convert x
__global__ void convert_f32_bf16(const float* __restrict__ in,
                                 unsigned short* __restrict__ out, int n4) {
    int i = blockIdx.x * blockDim.x + threadIdx.x;
    if (i >= n4) return;
    float4 v = reinterpret_cast<const float4*>(in)[i];
    ushort4 o;
    o.x = f2bf(v.x); o.y = f2bf(v.y); o.z = f2bf(v.z); o.w = f2bf(v.w);
    reinterpret_cast<ushort4*>(out)[i] = o;
}

// ------------------------------------------------- transpose + convert W
__global__ void transpose_convert(const float* __restrict__ in,
                                  unsigned short* __restrict__ out,
                                  int K, int N) {
    __shared__ float t[32][33];
    int n0 = blockIdx.x * 32, k0 = blockIdx.y * 32;
    t[threadIdx.y][threadIdx.x] = in[(size_t)(k0 + threadIdx.y) * N + (n0 + threadIdx.x)];
    __syncthreads();
    out[(size_t)(n0 + threadIdx.y) * K + (k0 + threadIdx.x)] = f2bf(t[threadIdx.x][threadIdx.y]);
}

// ---------------------------------------------------------------- GEMM
// C[M,N] = A[M,K] bf16 @ Bt[N,K]^T bf16 [+ bias] [cols<1024 scaled 0.125]
template <bool BIAS, bool OUT_BF16, bool QSCALE>
__global__ __launch_bounds__(256) void gemm_bt(const unsigned short* __restrict__ A,
                                               const unsigned short* __restrict__ Bt,
                                               const float* __restrict__ bias,
                                               void* __restrict__ Cv,
                                               int M, int N, int K) {
    __shared__ alignas(16) unsigned short As[128 * 32];
    __shared__ alignas(16) unsigned short Bs[128 * 32];

    const int t = threadIdx.x;
    const int lane = t & 63;
    const int wid = t >> 6;
    const int wr = wid >> 1, wc = wid & 1;
    const int m0 = blockIdx.y * 128, n0 = blockIdx.x * 128;

    f32x4 acc[4][4] = {};

    for (int k0 = 0; k0 < K; k0 += 32) {
#pragma unroll
        for (int i = 0; i < 2; ++i) {
            int c = i * 256 + t;
            int row = c >> 2;
            int col = (c & 3) * 8;
            const unsigned short* ga = A + (size_t)(m0 + row) * K + k0 + col;
            const unsigned short* gb = Bt + (size_t)(n0 + row) * K + k0 + col;
            __builtin_amdgcn_global_load_lds((gv_t*)ga, (lv_t*)(As + c * 8), 16, 0, 0);
            __builtin_amdgcn_global_load_lds((gv_t*)gb, (lv_t*)(Bs + c * 8), 16, 0, 0);
        }
        __syncthreads();

        bf16x8 af[4], bfr[4];
#pragma unroll
        for (int i = 0; i < 4; ++i)
            af[i] = *reinterpret_cast<const bf16x8*>(As + (wr * 64 + i * 16 + (lane & 15)) * 32 + (lane >> 4) * 8);
#pragma unroll
        for (int j = 0; j < 4; ++j)
            bfr[j] = *reinterpret_cast<const bf16x8*>(Bs + (wc * 64 + j * 16 + (lane & 15)) * 32 + (lane >> 4) * 8);
#pragma unroll
        for (int i = 0; i < 4; ++i)
#pragma unroll
            for (int j = 0; j < 4; ++j)
                acc[i][j] = __builtin_amdgcn_mfma_f32_16x16x32_bf16(af[i], bfr[j], acc[i][j], 0, 0, 0);
        __syncthreads();
    }

#pragma unroll
    for (int i = 0; i < 4; ++i) {
        int row = m0 + wr * 64 + i * 16 + (lane >> 4) * 4;
#pragma unroll
        for (int j = 0; j < 4; ++j) {
            int col = n0 + wc * 64 + j * 16 + (lane & 15);
            float bv = 0.0f;
            if (BIAS) bv = bias[col];
#pragma unroll
            for (int r = 0; r < 4; ++r) {
                float v = acc[i][j][r] + bv;
                if constexpr (QSCALE) { if (col < 1024) v *= 0.125f; }
                if constexpr (OUT_BF16)
                    ((unsigned short*)Cv)[(size_t)(row + r) * N + col] = f2bf(v);
                else
                    ((float*)Cv)[(size_t)(row + r) * N + col] = v;
            }
        }
    }
}

// ---------------------------------------------------------- flash attention
// KV-split flash attention (flash-decoding style). Block = (bh, qt, half):
// half 0 handles KV tiles [0, nh), half 1 handles [nh, qt+1). Writes
// normalized partial O' = O/l (bf16 [64q][64hd]) + (m, l) f32 per q-row.
// 2048 blocks at 4-resident/CU -> backfill balances the causal imbalance.
__global__ __launch_bounds__(256) void attn_partial(const unsigned short* __restrict__ qkv,
                                                    unsigned short* __restrict__ Opart,
                                                    float* __restrict__ ml,
                                                    int S) {
    const int TD = 3072, D = 1024;
    __shared__ alignas(16) unsigned short Ks[2][64 * 64];   // [kv][hd], swizzled
    __shared__ alignas(16) unsigned short Vt[2][64 * 64];   // [hd][kv], swizzled
    __shared__ alignas(16) unsigned short Ps[4][16 * 64];   // per-wave [q][kv], swizzled

    const int t = threadIdx.x, lane = t & 63, w = t >> 6;
    const int l15 = lane & 15, l4 = lane >> 4;
    const int sid = blockIdx.x;              // 0..63, LPT: long blocks first
    const int qt = 31 - (sid >> 1);
    const int half = sid & 1;
    const int bh = blockIdx.y;
    const int b = bh >> 4, h = bh & 15;

    const int nt = qt + 1;
    const int nh = (nt + 1) >> 1;
    const int jBeg = half ? nh : 0;
    const int jEnd = half ? nt : nh;

    const int pidx = (bh * 32 + qt) * 2 + half;
    unsigned short* Op = Opart + (size_t)pidx * 64 * 64;
    float* mlp = ml + (size_t)pidx * 128;

    if (jBeg >= jEnd) {                      // empty half: zero partial
        uint4 z = make_uint4(0, 0, 0, 0);
        reinterpret_cast<uint4*>(Op)[t] = z;
        reinterpret_cast<uint4*>(Op)[t + 256] = z;
        if (t < 64) { mlp[t * 2] = -1e30f; mlp[t * 2 + 1] = 0.0f; }
        return;
    }

    const size_t base = ((size_t)b * S) * TD + (size_t)h * 64;
    const unsigned short* qp = qkv + base;
    const unsigned short* kp = qkv + base + D;
    const unsigned short* vp = qkv + base + 2 * D;

    // Q fragments straight from global (B-operand layout: n=q=lane&15)
    bf16x8 aq[2];
    {
        const unsigned short* g = qp + (size_t)(qt * 64 + w * 16 + l15) * TD + l4 * 8;
        aq[0] = *reinterpret_cast<const bf16x8*>(g);
        aq[1] = *reinterpret_cast<const bf16x8*>(g + 32);
    }

    f32x4 oc[4] = {};                        // O^T frags: row=hd, col=q
    float mR = -1e30f, lR = 0.f;

    const float L2E = 1.44269504f;

    // ---- staging helpers
    auto stageK = [&](int j0, int buf) {
#pragma unroll
        for (int rnd = 0; rnd < 2; ++rnd) {
            int c = rnd * 256 + t;
            int row = c >> 3, hh = c & 7;
            const unsigned short* src = kp + (size_t)(j0 * 64 + row) * TD + ((hh ^ (row & 7)) * 8);
            __builtin_amdgcn_global_load_lds((gv_t*)src, (lv_t*)(Ks[buf] + c * 8), 16, 0, 0);
        }
    };
    const int v_hd = (t & 31) * 2, v_kvb = (t >> 5) * 8;
    unsigned int vv[8];
    auto loadV = [&](int j0) {
        const unsigned short* vsrc = vp + (size_t)(j0 * 64 + v_kvb) * TD + v_hd;
#pragma unroll
        for (int e = 0; e < 8; ++e)
            vv[e] = *reinterpret_cast<const unsigned int*>(vsrc + (size_t)e * TD);
    };
    auto writeV = [&](int buf) {
        unsigned int r0[4], r1[4];
#pragma unroll
        for (int i = 0; i < 4; ++i) {
            r0[i] = __builtin_amdgcn_perm(vv[2 * i + 1], vv[2 * i], 0x05040100u);
            r1[i] = __builtin_amdgcn_perm(vv[2 * i + 1], vv[2 * i], 0x07060302u);
        }
        int g0 = (v_kvb >> 3) ^ (v_hd & 7);
        int g1 = (v_kvb >> 3) ^ ((v_hd + 1) & 7);
        *reinterpret_cast<uint4*>(Vt[buf] + v_hd * 64 + g0 * 8) = make_uint4(r0[0], r0[1], r0[2], r0[3]);
        *reinterpret_cast<uint4*>(Vt[buf] + (v_hd + 1) * 64 + g1 * 8) = make_uint4(r1[0], r1[1], r1[2], r1[3]);
    };

    auto compute = [&](bool diag, int buf) {
        // ---- S^T = mfma(K, Q): lane holds kv = jn*16 + l4*4 + r for q = w*16+l15
        f32x4 sc[4];
        __builtin_amdgcn_s_setprio(1);
#pragma unroll
        for (int jn = 0; jn < 4; ++jn) {
            f32x4 s = {};
#pragma unroll
            for (int kk = 0; kk < 2; ++kk) {
                int row = jn * 16 + l15;
                int g = (kk * 4 + l4) ^ (l15 & 7);
                bf16x8 ak = *reinterpret_cast<const bf16x8*>(Ks[buf] + row * 64 + g * 8);
                s = __builtin_amdgcn_mfma_f32_16x16x32_bf16(ak, aq[kk], s, 0, 0, 0);
            }
            sc[jn] = s;
        }
        __builtin_amdgcn_s_setprio(0);
        if (diag) {
            int ql = w * 16 + l15;
#pragma unroll
            for (int jn = 0; jn < 4; ++jn)
#pragma unroll
                for (int r = 0; r < 4; ++r)
                    if (jn * 16 + l4 * 4 + r > ql) sc[jn][r] = -1e30f;
        }
        // ---- online softmax (lane-local row), defer-max (THR=8)
        float pm = -1e30f;
#pragma unroll
        for (int jn = 0; jn < 4; ++jn)
            pm = fmaxf(fmaxf(pm, fmaxf(sc[jn][0], sc[jn][1])),
                       fmaxf(sc[jn][2], sc[jn][3]));
        pm = fmaxf(pm, __shfl_xor(pm, 16));
        pm = fmaxf(pm, __shfl_xor(pm, 32));
        if (__any(pm > mR + 8.0f)) {         // rescale only when max grew
            float mnew = fmaxf(mR, pm);
            float alpha = exp2f((mR - mnew) * L2E);
            mR = mnew;
            lR *= alpha;
#pragma unroll
            for (int jc = 0; jc < 4; ++jc) oc[jc] *= alpha;
        }
        float mn2 = mR * L2E;
        float ps = 0.f;
#pragma unroll
        for (int jn = 0; jn < 4; ++jn) {
            float p0 = exp2f(sc[jn][0] * L2E - mn2);
            float p1 = exp2f(sc[jn][1] * L2E - mn2);
            float p2 = exp2f(sc[jn][2] * L2E - mn2);
            float p3 = exp2f(sc[jn][3] * L2E - mn2);
            sc[jn][0] = p0; sc[jn][1] = p1; sc[jn][2] = p2; sc[jn][3] = p3;
            ps += (p0 + p1) + (p2 + p3);
        }
        ps += __shfl_xor(ps, 16);
        ps += __shfl_xor(ps, 32);
        lR += ps;
        // ---- P^T -> Ps[w] via cvt_pk + b64 writes (granule-swizzled by q)
        const int q = l15;
#pragma unroll
        for (int jn = 0; jn < 4; ++jn) {
            unsigned int lo = cvt_pk_bf16(sc[jn][0], sc[jn][1]);
            unsigned int hi = cvt_pk_bf16(sc[jn][2], sc[jn][3]);
            int kv0 = jn * 16 + l4 * 4;
            int g = (kv0 >> 3) ^ (q & 7);
            *reinterpret_cast<uint2*>(Ps[w] + q * 64 + g * 8 + (kv0 & 7)) = make_uint2(lo, hi);
        }
        // ---- O^T += mfma(V^T, P)
        __builtin_amdgcn_s_setprio(1);
#pragma unroll
        for (int kk = 0; kk < 2; ++kk) {
            int gq = (kk * 4 + l4) ^ (q & 7);
            bf16x8 bp = *reinterpret_cast<const bf16x8*>(Ps[w] + q * 64 + gq * 8);
#pragma unroll
            for (int jc = 0; jc < 4; ++jc) {
                int hdrow = jc * 16 + l15;
                int gv = (kk * 4 + l4) ^ (l15 & 7);
                bf16x8 av = *reinterpret_cast<const bf16x8*>(Vt[buf] + hdrow * 64 + gv * 8);
                oc[jc] = __builtin_amdgcn_mfma_f32_16x16x32_bf16(av, bp, oc[jc], 0, 0, 0);
            }
        }
        __builtin_amdgcn_s_setprio(0);
    };

    // ---- prologue: stage tile jBeg into buf 0
    stageK(jBeg, 0);
    loadV(jBeg);
    writeV(0);
    __syncthreads();

    for (int j0 = jBeg; j0 < jEnd; ++j0) {
        const int cur = (j0 - jBeg) & 1, nxt = cur ^ 1;
        const bool have_next = (j0 + 1 < jEnd);
        if (have_next) {          // issue next tile's loads before compute
            stageK(j0 + 1, nxt);
            loadV(j0 + 1);
        }
        compute(j0 == qt, cur);
        if (have_next) writeV(nxt);   // waits vmcnt for vv, then ds_write
        __syncthreads();
    }

    // ---- epilogue: partial O' = O/l (bf16), plus (m, l)
    {
        float inv = 1.0f / lR;
        const int q = w * 16 + l15;
#pragma unroll
        for (int jc = 0; jc < 4; ++jc) {
            unsigned int pk0 = cvt_pk_bf16(oc[jc][0] * inv, oc[jc][1] * inv);
            unsigned int pk1 = cvt_pk_bf16(oc[jc][2] * inv, oc[jc][3] * inv);
            *reinterpret_cast<uint2*>(Op + q * 64 + jc * 16 + l4 * 4) = make_uint2(pk0, pk1);
        }
        if (l4 == 0) { mlp[q * 2] = mR; mlp[q * 2 + 1] = lR; }
    }
}

// ---------------------------------------------------------- combine partials
// ctx[q][hd] = (w0*O0' + w1*O1'), w_i = l_i * e^{m_i - m} / sum
__global__ __launch_bounds__(256) void attn_combine(const unsigned short* __restrict__ Opart,
                                                    const float* __restrict__ ml,
                                                    unsigned short* __restrict__ ctx,
                                                    int S) {
    const int D = 1024;
    const float L2E = 1.44269504f;
    const int qt = blockIdx.x, bh = blockIdx.y;
    const int b = bh >> 4, h = bh & 15;
    const int p0 = (bh * 32 + qt) * 2, p1 = p0 + 1;

    const int t = threadIdx.x;
    const int q = t >> 2, hd0 = (t & 3) * 16;

    float m0 = ml[p0 * 128 + q * 2], l0 = ml[p0 * 128 + q * 2 + 1];
    float m1 = ml[p1 * 128 + q * 2], l1 = ml[p1 * 128 + q * 2 + 1];
    float m = fmaxf(m0, m1);
    float w0 = (l0 > 0.f) ? l0 * exp2f((m0 - m) * L2E) : 0.f;
    float w1 = (l1 > 0.f) ? l1 * exp2f((m1 - m) * L2E) : 0.f;
    float inv = 1.0f / (w0 + w1);
    w0 *= inv; w1 *= inv;

    const unsigned short* O0 = Opart + (size_t)p0 * 4096 + q * 64 + hd0;
    const unsigned short* O1 = Opart + (size_t)p1 * 4096 + q * 64 + hd0;
    ushortx8 a0 = *reinterpret_cast<const ushortx8*>(O0);
    ushortx8 a1 = *reinterpret_cast<const ushortx8*>(O0 + 8);
    ushortx8 b0 = *reinterpret_cast<const ushortx8*>(O1);
    ushortx8 b1 = *reinterpret_cast<const ushortx8*>(O1 + 8);

    unsigned int outw[8];
#pragma unroll
    for (int i = 0; i < 4; ++i) {
        float x0 = w0 * bf2f(a0[2 * i])     + w1 * bf2f(b0[2 * i]);
        float x1 = w0 * bf2f(a0[2 * i + 1]) + w1 * bf2f(b0[2 * i + 1]);
        outw[i] = cvt_pk_bf16(x0, x1);
        float y0 = w0 * bf2f(a1[2 * i])     + w1 * bf2f(b1[2 * i]);
        float y1 = w0 * bf2f(a1[2 * i + 1]) + w1 * bf2f(b1[2 * i + 1]);
        outw[4 + i] = cvt_pk_bf16(y0, y1);
    }
    unsigned short* crow = ctx + ((size_t)b * S + qt * 64 + q) * D + h * 64 + hd0;
    *reinterpret_cast<uint4*>(crow) = make_uint4(outw[0], outw[1], outw[2], outw[3]);
    *reinterpret_cast<uint4*>(crow + 8) = make_uint4(outw[4], outw[5], outw[6], outw[7]);
}

// ---------------------------------------------------------------- launch
extern "C" void kernel_launch(void* const* d_in, const int* in_sizes, int n_in,
                              void* d_out, int out_size, void* d_ws, size_t ws_size,
                              hipStream_t stream) {
    const float* x = (const float*)d_in[0];
    const float* Wqkv = (const float*)d_in[1];
    const float* bqkv = (const float*)d_in[2];
    const float* Wout = (const float*)d_in[3];
    float* out = (float*)d_out;

    const int B = 2, S = 2048, D = 1024, TD = 3072;
    const int M = B * S;  // 4096

    char* ws = (char*)d_ws;
    unsigned short* x_bf  = (unsigned short*)(ws);               // 8 MiB
    unsigned short* wqkvT = (unsigned short*)(ws + 8388608);     // 6 MiB  [3072][1024]
    unsigned short* woutT = (unsigned short*)(ws + 14680064);    // 2 MiB  [1024][1024]
    unsigned short* qkv   = (unsigned short*)(ws + 16777216);    // 24 MiB [4096][3072]
    unsigned short* ctx   = (unsigned short*)(ws + 41943040);    // 8 MiB  [4096][1024]
    // Opart aliases [0, 16777216) = x_bf+wqkvT+woutT (dead after GEMM1;
    // woutT is recreated AFTER combine). 2048 partials x 64x64 bf16 = exact fit.
    unsigned short* Opart = (unsigned short*)(ws);
    float* ml             = (float*)(ws + 50331648);             // 1 MiB

    convert_f32_bf16<<<dim3((M * D / 4 + 255) / 256), dim3(256), 0, stream>>>(x, x_bf, M * D / 4);
    transpose_convert<<<dim3(TD / 32, D / 32), dim3(32, 32), 0, stream>>>(Wqkv, wqkvT, D, TD);

    gemm_bt<true, true, true><<<dim3(TD / 128, M / 128), dim3(256), 0, stream>>>(
        x_bf, wqkvT, bqkv, (void*)qkv, M, TD, D);

    attn_partial<<<dim3(64, 32), dim3(256), 0, stream>>>(qkv, Opart, ml, S);
    attn_combine<<<dim3(32, 32), dim3(256), 0, stream>>>(Opart, ml, ctx, S);

    transpose_convert<<<dim3(D / 32, D / 32), dim3(32, 32), 0, stream>>>(Wout, woutT, D, D);

    gemm_bt<false, false, false><<<dim3(D / 128, M / 128), dim3(256), 0, stream>>>(
        ctx, woutT, nullptr, (void*)out, M, D, D);
}

// Round 9
// 139.848 us; speedup vs baseline: 1.1509x; 1.1233x over previous
//
#include <hip/hip_runtime.h>
#include <hip/hip_bf16.h>

typedef __bf16 bf16x8 __attribute__((ext_vector_type(8)));
typedef float f32x4 __attribute__((ext_vector_type(4)));

typedef __attribute__((address_space(1))) void gv_t;
typedef __attribute__((address_space(3))) void lv_t;

__device__ __forceinline__ unsigned short f2bf(float f) {
    unsigned int u = __float_as_uint(f);
    unsigned int r = (u + 0x7fffu + ((u >> 16) & 1u)) >> 16;
    return (unsigned short)r;
}

__device__ __forceinline__ unsigned int cvt_pk_bf16(float a, float b) {
    unsigned int r;
    asm("v_cvt_pk_bf16_f32 %0, %1, %2" : "=v"(r) : "v"(a), "v"(b));
    return r;
}

// ---------------------------------------------------------------- convert x
__global__ void convert_f32_bf16(const float* __restrict__ in,
                                 unsigned short* __restrict__ out, int n4) {
    int i = blockIdx.x * blockDim.x + threadIdx.x;
    if (i >= n4) return;
    float4 v = reinterpret_cast<const float4*>(in)[i];
    ushort4 o;
    o.x = f2bf(v.x); o.y = f2bf(v.y); o.z = f2bf(v.z); o.w = f2bf(v.w);
    reinterpret_cast<ushort4*>(out)[i] = o;
}

// ------------------------------------------------- transpose + convert W
__global__ void transpose_convert(const float* __restrict__ in,
                                  unsigned short* __restrict__ out,
                                  int K, int N) {
    __shared__ float t[32][33];
    int n0 = blockIdx.x * 32, k0 = blockIdx.y * 32;
    t[threadIdx.y][threadIdx.x] = in[(size_t)(k0 + threadIdx.y) * N + (n0 + threadIdx.x)];
    __syncthreads();
    out[(size_t)(n0 + threadIdx.y) * K + (k0 + threadIdx.x)] = f2bf(t[threadIdx.x][threadIdx.y]);
}

// ---------------------------------------------------------------- GEMM
// C[M,N] = A[M,K] bf16 @ Bt[N,K]^T bf16 [+ bias] [cols<1024 scaled 0.125]
template <bool BIAS, bool OUT_BF16, bool QSCALE>
__global__ __launch_bounds__(256) void gemm_bt(const unsigned short* __restrict__ A,
                                               const unsigned short* __restrict__ Bt,
                                               const float* __restrict__ bias,
                                               void* __restrict__ Cv,
                                               int M, int N, int K) {
    __shared__ alignas(16) unsigned short As[128 * 32];
    __shared__ alignas(16) unsigned short Bs[128 * 32];

    const int t = threadIdx.x;
    const int lane = t & 63;
    const int wid = t >> 6;
    const int wr = wid >> 1, wc = wid & 1;
    const int m0 = blockIdx.y * 128, n0 = blockIdx.x * 128;

    f32x4 acc[4][4] = {};

    for (int k0 = 0; k0 < K; k0 += 32) {
#pragma unroll
        for (int i = 0; i < 2; ++i) {
            int c = i * 256 + t;
            int row = c >> 2;
            int col = (c & 3) * 8;
            const unsigned short* ga = A + (size_t)(m0 + row) * K + k0 + col;
            const unsigned short* gb = Bt + (size_t)(n0 + row) * K + k0 + col;
            __builtin_amdgcn_global_load_lds((gv_t*)ga, (lv_t*)(As + c * 8), 16, 0, 0);
            __builtin_amdgcn_global_load_lds((gv_t*)gb, (lv_t*)(Bs + c * 8), 16, 0, 0);
        }
        __syncthreads();

        bf16x8 af[4], bfr[4];
#pragma unroll
        for (int i = 0; i < 4; ++i)
            af[i] = *reinterpret_cast<const bf16x8*>(As + (wr * 64 + i * 16 + (lane & 15)) * 32 + (lane >> 4) * 8);
#pragma unroll
        for (int j = 0; j < 4; ++j)
            bfr[j] = *reinterpret_cast<const bf16x8*>(Bs + (wc * 64 + j * 16 + (lane & 15)) * 32 + (lane >> 4) * 8);
#pragma unroll
        for (int i = 0; i < 4; ++i)
#pragma unroll
            for (int j = 0; j < 4; ++j)
                acc[i][j] = __builtin_amdgcn_mfma_f32_16x16x32_bf16(af[i], bfr[j], acc[i][j], 0, 0, 0);
        __syncthreads();
    }

#pragma unroll
    for (int i = 0; i < 4; ++i) {
        int row = m0 + wr * 64 + i * 16 + (lane >> 4) * 4;
#pragma unroll
        for (int j = 0; j < 4; ++j) {
            int col = n0 + wc * 64 + j * 16 + (lane & 15);
            float bv = 0.0f;
            if (BIAS) bv = bias[col];
#pragma unroll
            for (int r = 0; r < 4; ++r) {
                float v = acc[i][j][r] + bv;
                if constexpr (QSCALE) { if (col < 1024) v *= 0.125f; }
                if constexpr (OUT_BF16)
                    ((unsigned short*)Cv)[(size_t)(row + r) * N + col] = f2bf(v);
                else
                    ((float*)Cv)[(size_t)(row + r) * N + col] = v;
            }
        }
    }
}

// ---------------------------------------------------------- flash attention
// Swapped-operand flash attn. 8 waves (512 thr): waves 0-3 own q-tile QT_hi,
// waves 4-7 own QT_lo (paired {pid, 31-pid}); the two tiles run CONCURRENTLY
// on the wave halves (R3 ran them serially). K/V double-buffered + async
// stage split; defer-max; shfl_xor softmax reduce (proven path).
__global__ __launch_bounds__(512) void attn_fwd(const unsigned short* __restrict__ qkv,
                                                unsigned short* __restrict__ ctx,
                                                int S) {
    const int TD = 3072, D = 1024;
    __shared__ alignas(16) unsigned short Ks[2][64 * 64];   // [kv][hd], swizzled
    __shared__ alignas(16) unsigned short Vt[2][64 * 64];   // [hd][kv], swizzled
    __shared__ alignas(16) unsigned short Ps[8][16 * 64];   // per-wave [q][kv], swizzled

    const int t = threadIdx.x, lane = t & 63;
    const int w_all = t >> 6;            // 0..7
    const int w_loc = w_all & 3;         // wave's 16-row slice within its tile
    const bool is_hi = (w_all < 4);
    const int l15 = lane & 15, l4 = lane >> 4;
    const int pid = blockIdx.x;          // 0..15
    const int bh = blockIdx.y;
    const int b = bh >> 4, h = bh & 15;
    const int QT_lo = pid, QT_hi = 31 - pid;
    const int QT = is_hi ? QT_hi : QT_lo;

    const size_t base = ((size_t)b * S) * TD + (size_t)h * 64;
    const unsigned short* qp = qkv + base;
    const unsigned short* kp = qkv + base + D;
    const unsigned short* vp = qkv + base + 2 * D;

    // Q fragments straight from global (B-operand layout: n=q=lane&15)
    bf16x8 aq[2];
    {
        const unsigned short* g = qp + (size_t)(QT * 64 + w_loc * 16 + l15) * TD + l4 * 8;
        aq[0] = *reinterpret_cast<const bf16x8*>(g);
        aq[1] = *reinterpret_cast<const bf16x8*>(g + 32);
    }

    f32x4 oc[4] = {};                    // O^T frags: row=hd, col=q
    float mR = -1e30f, lR = 0.f;
    const float L2E = 1.44269504f;

    // ---- staging helpers (512 threads block-wide)
    auto stageK = [&](int j0, int buf) {
        int c = t;                       // 512 chunks of 8 elems = 64x64
        int row = c >> 3, hh = c & 7;
        const unsigned short* src = kp + (size_t)(j0 * 64 + row) * TD + ((hh ^ (row & 7)) * 8);
        __builtin_amdgcn_global_load_lds((gv_t*)src, (lv_t*)(Ks[buf] + c * 8), 16, 0, 0);
    };
    const int v_hd = (t & 31) * 2, v_kvb = (t >> 5) * 4;   // 16 kv-quads x 32 hd-pairs
    unsigned int vv[4];
    auto loadV = [&](int j0) {
        const unsigned short* vsrc = vp + (size_t)(j0 * 64 + v_kvb) * TD + v_hd;
#pragma unroll
        for (int e = 0; e < 4; ++e)
            vv[e] = *reinterpret_cast<const unsigned int*>(vsrc + (size_t)e * TD);
    };
    auto writeV = [&](int buf) {
        unsigned int r0a = __builtin_amdgcn_perm(vv[1], vv[0], 0x05040100u);
        unsigned int r0b = __builtin_amdgcn_perm(vv[3], vv[2], 0x05040100u);
        unsigned int r1a = __builtin_amdgcn_perm(vv[1], vv[0], 0x07060302u);
        unsigned int r1b = __builtin_amdgcn_perm(vv[3], vv[2], 0x07060302u);
        int g0 = (v_kvb >> 3) ^ (v_hd & 7);
        int g1 = (v_kvb >> 3) ^ ((v_hd + 1) & 7);
        int sub = v_kvb & 7;             // 0 or 4
        *reinterpret_cast<uint2*>(Vt[buf] + v_hd * 64 + g0 * 8 + sub) = make_uint2(r0a, r0b);
        *reinterpret_cast<uint2*>(Vt[buf] + (v_hd + 1) * 64 + g1 * 8 + sub) = make_uint2(r1a, r1b);
    };

    auto compute = [&](bool diag, int buf) {
        // ---- S^T = mfma(K, Q): lane holds kv = jn*16 + l4*4 + r for its q
        f32x4 sc[4];
        __builtin_amdgcn_s_setprio(1);
#pragma unroll
        for (int jn = 0; jn < 4; ++jn) {
            f32x4 s = {};
#pragma unroll
            for (int kk = 0; kk < 2; ++kk) {
                int row = jn * 16 + l15;
                int g = (kk * 4 + l4) ^ (l15 & 7);
                bf16x8 ak = *reinterpret_cast<const bf16x8*>(Ks[buf] + row * 64 + g * 8);
                s = __builtin_amdgcn_mfma_f32_16x16x32_bf16(ak, aq[kk], s, 0, 0, 0);
            }
            sc[jn] = s;
        }
        __builtin_amdgcn_s_setprio(0);
        if (diag) {
            int ql = w_loc * 16 + l15;
#pragma unroll
            for (int jn = 0; jn < 4; ++jn)
#pragma unroll
                for (int r = 0; r < 4; ++r)
                    if (jn * 16 + l4 * 4 + r > ql) sc[jn][r] = -1e30f;
        }
        // ---- online softmax (row on 4 lanes sharing l15), defer-max (THR=8)
        float pm = -1e30f;
#pragma unroll
        for (int jn = 0; jn < 4; ++jn)
            pm = fmaxf(fmaxf(pm, fmaxf(sc[jn][0], sc[jn][1])),
                       fmaxf(sc[jn][2], sc[jn][3]));
        pm = fmaxf(pm, __shfl_xor(pm, 16));
        pm = fmaxf(pm, __shfl_xor(pm, 32));
        if (__any(pm > mR + 8.0f)) {     // rescale only when max grew
            float mnew = fmaxf(mR, pm);
            float alpha = exp2f((mR - mnew) * L2E);
            mR = mnew;
            lR *= alpha;
#pragma unroll
            for (int jc = 0; jc < 4; ++jc) oc[jc] *= alpha;
        }
        float mn2 = mR * L2E;
        float ps = 0.f;
#pragma unroll
        for (int jn = 0; jn < 4; ++jn) {
            float p0 = exp2f(sc[jn][0] * L2E - mn2);
            float p1 = exp2f(sc[jn][1] * L2E - mn2);
            float p2 = exp2f(sc[jn][2] * L2E - mn2);
            float p3 = exp2f(sc[jn][3] * L2E - mn2);
            sc[jn][0] = p0; sc[jn][1] = p1; sc[jn][2] = p2; sc[jn][3] = p3;
            ps += (p0 + p1) + (p2 + p3);
        }
        ps += __shfl_xor(ps, 16);
        ps += __shfl_xor(ps, 32);
        lR += ps;
        // ---- P^T -> Ps[w_all] via cvt_pk + b64 writes (granule-swizzled by q)
        const int q = l15;
#pragma unroll
        for (int jn = 0; jn < 4; ++jn) {
            unsigned int lo = cvt_pk_bf16(sc[jn][0], sc[jn][1]);
            unsigned int hi = cvt_pk_bf16(sc[jn][2], sc[jn][3]);
            int kv0 = jn * 16 + l4 * 4;
            int g = (kv0 >> 3) ^ (q & 7);
            *reinterpret_cast<uint2*>(Ps[w_all] + q * 64 + g * 8 + (kv0 & 7)) = make_uint2(lo, hi);
        }
        // ---- O^T += mfma(V^T, P)
        __builtin_amdgcn_s_setprio(1);
#pragma unroll
        for (int kk = 0; kk < 2; ++kk) {
            int gq = (kk * 4 + l4) ^ (q & 7);
            bf16x8 bp = *reinterpret_cast<const bf16x8*>(Ps[w_all] + q * 64 + gq * 8);
#pragma unroll
            for (int jc = 0; jc < 4; ++jc) {
                int hdrow = jc * 16 + l15;
                int gv = (kk * 4 + l4) ^ (l15 & 7);
                bf16x8 av = *reinterpret_cast<const bf16x8*>(Vt[buf] + hdrow * 64 + gv * 8);
                oc[jc] = __builtin_amdgcn_mfma_f32_16x16x32_bf16(av, bp, oc[jc], 0, 0, 0);
            }
        }
        __builtin_amdgcn_s_setprio(0);
    };

    // ---- prologue: stage tile 0 into buf 0
    stageK(0, 0);
    loadV(0);
    writeV(0);
    __syncthreads();

    for (int j0 = 0; j0 <= QT_hi; ++j0) {
        const int cur = j0 & 1, nxt = cur ^ 1;
        const bool have_next = (j0 < QT_hi);
        if (have_next) {             // issue next tile's loads before compute
            stageK(j0 + 1, nxt);
            loadV(j0 + 1);
        }
        if (j0 <= QT) compute(j0 == QT, cur);   // hi waves: always; lo: early out
        if (have_next) writeV(nxt);  // waits vmcnt for vv, then ds_write
        __syncthreads();
    }

    // ---- epilogue: ctx[q][hd] = O^T / l  (cvt_pk + b64 stores)
    {
        float inv = 1.0f / lR;
        size_t qg = (size_t)QT * 64 + w_loc * 16 + l15;
        unsigned short* crow = ctx + ((size_t)b * S + qg) * D + h * 64;
#pragma unroll
        for (int jc = 0; jc < 4; ++jc) {
            unsigned int pk0 = cvt_pk_bf16(oc[jc][0] * inv, oc[jc][1] * inv);
            unsigned int pk1 = cvt_pk_bf16(oc[jc][2] * inv, oc[jc][3] * inv);
            *reinterpret_cast<uint2*>(crow + jc * 16 + l4 * 4) = make_uint2(pk0, pk1);
        }
    }
}

// ---------------------------------------------------------------- launch
extern "C" void kernel_launch(void* const* d_in, const int* in_sizes, int n_in,
                              void* d_out, int out_size, void* d_ws, size_t ws_size,
                              hipStream_t stream) {
    const float* x = (const float*)d_in[0];
    const float* Wqkv = (const float*)d_in[1];
    const float* bqkv = (const float*)d_in[2];
    const float* Wout = (const float*)d_in[3];
    float* out = (float*)d_out;

    const int B = 2, S = 2048, D = 1024, TD = 3072;
    const int M = B * S;  // 4096

    char* ws = (char*)d_ws;
    unsigned short* x_bf  = (unsigned short*)(ws);               // 8 MiB
    unsigned short* wqkvT = (unsigned short*)(ws + 8388608);     // 6 MiB  [3072][1024]
    unsigned short* woutT = (unsigned short*)(ws + 14680064);    // 2 MiB  [1024][1024]
    unsigned short* qkv   = (unsigned short*)(ws + 16777216);    // 24 MiB [4096][3072]
    unsigned short* ctx   = (unsigned short*)(ws + 41943040);    // 8 MiB  [4096][1024]

    convert_f32_bf16<<<dim3((M * D / 4 + 255) / 256), dim3(256), 0, stream>>>(x, x_bf, M * D / 4);
    transpose_convert<<<dim3(TD / 32, D / 32), dim3(32, 32), 0, stream>>>(Wqkv, wqkvT, D, TD);
    transpose_convert<<<dim3(D / 32, D / 32), dim3(32, 32), 0, stream>>>(Wout, woutT, D, D);

    gemm_bt<true, true, true><<<dim3(TD / 128, M / 128), dim3(256), 0, stream>>>(
        x_bf, wqkvT, bqkv, (void*)qkv, M, TD, D);

    attn_fwd<<<dim3(16, 32), dim3(512), 0, stream>>>(qkv, ctx, S);

    gemm_bt<false, false, false><<<dim3(D / 128, M / 128), dim3(256), 0, stream>>>(
        ctx, woutT, nullptr, (void*)out, M, D, D);
}